// Round 1
// baseline (844.065 us; speedup 1.0000x reference)
//
#include <hip/hip_runtime.h>
#include <hip/hip_bf16.h>

#define H 256
#define NSC 512
#define MQ 4096
#define BATCH 4
#define CN 16
#define TQ 32

// C[M,Nout] = relu?((A[M,K] @ W[Nout,K]^T + bias) * alpha)
// 64x64 tile, BK=32, 4x4 per thread. LDS stored K-major (transposed) so the
// inner loop is 2x ds_read_b128 + 16 v_fma per k.
__global__ __launch_bounds__(256) void gemm_bias_kernel(
    const float* __restrict__ A, const float* __restrict__ W,
    const float* __restrict__ bias, float* __restrict__ C,
    int K, int Nout, float alpha, int relu)
{
    __shared__ float As[32][68];   // [k][row], stride 68 keeps float4 alignment
    __shared__ float Ws[32][68];   // [k][col]
    const int t = threadIdx.x;
    const int ty = t >> 4, tx = t & 15;
    const int rowBase = blockIdx.y * 64;
    const int colBase = blockIdx.x * 64;
    const int lr = t >> 2;          // 0..63
    const int lc = (t & 3) * 8;     // 0,8,16,24
    const float* Ap = A + (size_t)(rowBase + lr) * K + lc;
    const float* Wp = W + (size_t)(colBase + lr) * K + lc;
    float acc[4][4] = {{0.f}};
    for (int k0 = 0; k0 < K; k0 += 32) {
        float4 a0 = *(const float4*)(Ap + k0);
        float4 a1 = *(const float4*)(Ap + k0 + 4);
        float4 w0 = *(const float4*)(Wp + k0);
        float4 w1 = *(const float4*)(Wp + k0 + 4);
        __syncthreads();
        As[lc+0][lr]=a0.x; As[lc+1][lr]=a0.y; As[lc+2][lr]=a0.z; As[lc+3][lr]=a0.w;
        As[lc+4][lr]=a1.x; As[lc+5][lr]=a1.y; As[lc+6][lr]=a1.z; As[lc+7][lr]=a1.w;
        Ws[lc+0][lr]=w0.x; Ws[lc+1][lr]=w0.y; Ws[lc+2][lr]=w0.z; Ws[lc+3][lr]=w0.w;
        Ws[lc+4][lr]=w1.x; Ws[lc+5][lr]=w1.y; Ws[lc+6][lr]=w1.z; Ws[lc+7][lr]=w1.w;
        __syncthreads();
        #pragma unroll
        for (int kk = 0; kk < 32; kk++) {
            float4 av = *(const float4*)&As[kk][ty*4];
            float4 wv = *(const float4*)&Ws[kk][tx*4];
            acc[0][0] += av.x*wv.x; acc[0][1] += av.x*wv.y; acc[0][2] += av.x*wv.z; acc[0][3] += av.x*wv.w;
            acc[1][0] += av.y*wv.x; acc[1][1] += av.y*wv.y; acc[1][2] += av.y*wv.z; acc[1][3] += av.y*wv.w;
            acc[2][0] += av.z*wv.x; acc[2][1] += av.z*wv.y; acc[2][2] += av.z*wv.z; acc[2][3] += av.z*wv.w;
            acc[3][0] += av.w*wv.x; acc[3][1] += av.w*wv.y; acc[3][2] += av.w*wv.z; acc[3][3] += av.w*wv.w;
        }
    }
    const int c0 = colBase + tx * 4;
    const float b0 = bias[c0], b1 = bias[c0+1], b2 = bias[c0+2], b3 = bias[c0+3];
    #pragma unroll
    for (int i = 0; i < 4; i++) {
        float4 o;
        o.x = (acc[i][0] + b0) * alpha;
        o.y = (acc[i][1] + b1) * alpha;
        o.z = (acc[i][2] + b2) * alpha;
        o.w = (acc[i][3] + b3) * alpha;
        if (relu) { o.x=fmaxf(o.x,0.f); o.y=fmaxf(o.y,0.f); o.z=fmaxf(o.z,0.f); o.w=fmaxf(o.w,0.f); }
        *(float4*)&C[(size_t)(rowBase + ty*4 + i) * Nout + c0] = o;
    }
}

// Fused cross-attention. One block = 32 queries x all 8 heads of one batch.
// thread t -> (e = t>>5, q = t&31): K/V LDS reads are wave-broadcast.
// Pass 1: unnormalized exp (scores ~ N(0,1): exp safe in fp32 without max
// subtraction) accumulating l and ctx. Pass 2: recompute scores, write
// mean-over-heads attn probabilities.
__global__ __launch_bounds__(256) void attn_kernel(
    const float* __restrict__ q, const float* __restrict__ k,
    const float* __restrict__ v, float* __restrict__ ctx_out,
    float* __restrict__ attn_score)
{
    __shared__ float Ks[CN][H];
    __shared__ float Vs[CN][H];
    __shared__ float ps[TQ][CN];
    const int t = threadIdx.x;
    const int b = blockIdx.x >> 7;              // 128 tiles per batch
    const int m0 = (blockIdx.x & 127) * TQ;
    const int e = t >> 5;
    const int qi = t & 31;
    const size_t row = (size_t)b * MQ + m0 + qi;
    float qreg[32];
    {
        const float4* qp = (const float4*)(q + row * H + e * 32);
        #pragma unroll
        for (int i = 0; i < 8; i++) *(float4*)&qreg[i*4] = qp[i];
    }
    const float* kb = k + (size_t)b * NSC * H;
    const float* vb = v + (size_t)b * NSC * H;
    float l = 0.f;
    float ctx[32];
    #pragma unroll
    for (int i = 0; i < 32; i++) ctx[i] = 0.f;

    for (int c = 0; c < NSC / CN; c++) {
        __syncthreads();
        #pragma unroll
        for (int i = 0; i < 4; i++) {
            int idx = t + 256 * i;               // float4 index, 1024 total
            int r = idx >> 6, col = (idx & 63) * 4;
            *(float4*)&Ks[r][col] = *(const float4*)&kb[(size_t)(c*CN + r) * H + col];
            *(float4*)&Vs[r][col] = *(const float4*)&vb[(size_t)(c*CN + r) * H + col];
        }
        __syncthreads();
        for (int n = 0; n < CN; n++) {
            const float4* kr = (const float4*)&Ks[n][e*32];
            float s = 0.f;
            #pragma unroll
            for (int j = 0; j < 8; j++) {
                float4 kv = kr[j];
                s += qreg[j*4+0]*kv.x + qreg[j*4+1]*kv.y + qreg[j*4+2]*kv.z + qreg[j*4+3]*kv.w;
            }
            float w = __expf(s);
            l += w;
            const float4* vr = (const float4*)&Vs[n][e*32];
            #pragma unroll
            for (int j = 0; j < 8; j++) {
                float4 vv = vr[j];
                ctx[j*4+0] += w*vv.x; ctx[j*4+1] += w*vv.y; ctx[j*4+2] += w*vv.z; ctx[j*4+3] += w*vv.w;
            }
        }
    }
    const float inv_l = 1.f / l;
    {
        float4* cp = (float4*)(ctx_out + row * H + e * 32);
        #pragma unroll
        for (int i = 0; i < 8; i++) {
            float4 o;
            o.x = ctx[i*4+0]*inv_l; o.y = ctx[i*4+1]*inv_l;
            o.z = ctx[i*4+2]*inv_l; o.w = ctx[i*4+3]*inv_l;
            cp[i] = o;
        }
    }
    // pass 2: attn_score = mean over heads of normalized probs
    float* psf = &ps[0][0];
    for (int c = 0; c < NSC / CN; c++) {
        __syncthreads();   // prior iter's ps readout + Ks reads complete
        #pragma unroll
        for (int i = 0; i < 4; i++) {
            int idx = t + 256 * i;
            int r = idx >> 6, col = (idx & 63) * 4;
            *(float4*)&Ks[r][col] = *(const float4*)&kb[(size_t)(c*CN + r) * H + col];
        }
        psf[t] = 0.f;
        psf[t + 256] = 0.f;
        __syncthreads();
        for (int n = 0; n < CN; n++) {
            const float4* kr = (const float4*)&Ks[n][e*32];
            float s = 0.f;
            #pragma unroll
            for (int j = 0; j < 8; j++) {
                float4 kv = kr[j];
                s += qreg[j*4+0]*kv.x + qreg[j*4+1]*kv.y + qreg[j*4+2]*kv.z + qreg[j*4+3]*kv.w;
            }
            float w = __expf(s) * inv_l;
            w += __shfl_xor(w, 32);              // fold the wave's two heads
            if ((t & 32) == 0) atomicAdd(&ps[qi][n], w * 0.125f);
        }
        __syncthreads();
        {
            int qw = t >> 3;
            int col = (t & 7) * 2;
            float2 o = *(float2*)&ps[qw][col];
            *(float2*)&attn_score[((size_t)b*MQ + m0 + qw) * NSC + c*CN + col] = o;
        }
    }
}

// out = LN(a + bres) * g + beta, rows of H=256, one row per block
__global__ __launch_bounds__(256) void add_ln_kernel(
    const float* __restrict__ a, const float* __restrict__ bres,
    const float* __restrict__ g, const float* __restrict__ beta,
    float* __restrict__ out)
{
    __shared__ float red[8];
    const int r = blockIdx.x, t = threadIdx.x;
    float vv = a[(size_t)r*H + t] + bres[(size_t)r*H + t];
    float s = vv;
    #pragma unroll
    for (int o = 32; o > 0; o >>= 1) s += __shfl_down(s, o, 64);
    __syncthreads();
    if ((t & 63) == 0) red[t >> 6] = s;
    __syncthreads();
    float mu = (red[0] + red[1] + red[2] + red[3]) * (1.f / 256.f);
    float d = vv - mu;
    float s2 = d * d;
    #pragma unroll
    for (int o = 32; o > 0; o >>= 1) s2 += __shfl_down(s2, o, 64);
    __syncthreads();
    if ((t & 63) == 0) red[t >> 6] = s2;
    __syncthreads();
    float var = (red[0] + red[1] + red[2] + red[3]) * (1.f / 256.f);
    out[(size_t)r*H + t] = d * rsqrtf(var + 1e-6f) * g[t] + beta[t];
}

extern "C" void kernel_launch(void* const* d_in, const int* in_sizes, int n_in,
                              void* d_out, int out_size, void* d_ws, size_t ws_size,
                              hipStream_t stream)
{
    const float* hidden = (const float*)d_in[0];
    const float* scene  = (const float*)d_in[1];
    const float* in_w   = (const float*)d_in[2];
    const float* in_b   = (const float*)d_in[3];
    const float* out_w  = (const float*)d_in[4];
    const float* out_b  = (const float*)d_in[5];
    const float* aln_g  = (const float*)d_in[6];
    const float* aln_b  = (const float*)d_in[7];
    const float* ff1_w  = (const float*)d_in[8];
    const float* ff1_b  = (const float*)d_in[9];
    const float* ff2_w  = (const float*)d_in[10];
    const float* ff2_b  = (const float*)d_in[11];
    const float* fln_g  = (const float*)d_in[12];
    const float* fln_b  = (const float*)d_in[13];

    float* out0  = (float*)d_out;
    float* score = out0 + (size_t)BATCH * MQ * H;          // second output

    float* ws  = (float*)d_ws;
    float* qb  = ws;                                       // 16384x256 (aliased attn_out)
    float* kb  = qb  + (size_t)BATCH * MQ  * H;            // 2048x256
    float* vb  = kb  + (size_t)BATCH * NSC * H;            // 2048x256
    float* ctx = vb  + (size_t)BATCH * NSC * H;            // 16384x256 (aliased ff out y)
    float* xb  = ctx + (size_t)BATCH * MQ  * H;            // 16384x256
    float* fb  = xb  + (size_t)BATCH * MQ  * H;            // 16384x128
    // total ws use: ~60 MB

    const float scale = 0.17677669529663687f;              // 1/sqrt(32)
    dim3 blk(256);

    // q = (hidden @ Wq^T + bq) * scale
    gemm_bias_kernel<<<dim3(4, 256), blk, 0, stream>>>(hidden, in_w,            in_b,       qb, 256, 256, scale, 0);
    // k, v
    gemm_bias_kernel<<<dim3(4, 32),  blk, 0, stream>>>(scene,  in_w + 256*256,  in_b + 256, kb, 256, 256, 1.f, 0);
    gemm_bias_kernel<<<dim3(4, 32),  blk, 0, stream>>>(scene,  in_w + 512*256,  in_b + 512, vb, 256, 256, 1.f, 0);
    // fused attention -> ctx + attn_score
    attn_kernel<<<dim3(512), blk, 0, stream>>>(qb, kb, vb, ctx, score);
    // attn_out = ctx @ Wout^T + bout   (into qb; q is dead)
    gemm_bias_kernel<<<dim3(4, 256), blk, 0, stream>>>(ctx, out_w, out_b, qb, 256, 256, 1.f, 0);
    // x = LN(attn_out + hidden)
    add_ln_kernel<<<dim3(16384), blk, 0, stream>>>(qb, hidden, aln_g, aln_b, xb);
    // f = relu(x @ W1^T + b1)
    gemm_bias_kernel<<<dim3(2, 256), blk, 0, stream>>>(xb, ff1_w, ff1_b, fb, 256, 128, 1.f, 1);
    // y = f @ W2^T + b2   (into ctx; ctx is dead)
    gemm_bias_kernel<<<dim3(4, 256), blk, 0, stream>>>(fb, ff2_w, ff2_b, ctx, 128, 256, 1.f, 0);
    // out = LN(y + x)
    add_ln_kernel<<<dim3(16384), blk, 0, stream>>>(ctx, xb, fln_g, fln_b, out0);
}

// Round 2
// 308.346 us; speedup vs baseline: 2.7374x; 2.7374x over previous
//
#include <hip/hip_runtime.h>
#include <hip/hip_bf16.h>

#define H 256
#define NSC 512
#define MQ 4096
#define BATCH 4

typedef __attribute__((ext_vector_type(8))) short bf16x8;
typedef __attribute__((ext_vector_type(4))) float f32x4;

__device__ __forceinline__ ushort f2bf(float x) {
    union { float f; unsigned u; } c; c.f = x;
    unsigned r = c.u + 0x7FFF + ((c.u >> 16) & 1);   // RNE
    return (ushort)(r >> 16);
}
__device__ __forceinline__ float bf2f(ushort u) {
    union { unsigned u; float f; } c; c.u = ((unsigned)u) << 16;
    return c.f;
}

// C[M,Nout] = relu?((A[M,K] @ W[Nout,K]^T + bias) * alpha)
// out_mode: 0 = fp32 row-major, 1 = bf16 row-major, 2 = bf16 transposed per
// batch: vT[b=row>>9][col][key=row&511] (for V so attn reads columns cleanly)
__global__ __launch_bounds__(256) void gemm_bias_kernel(
    const float* __restrict__ A, const float* __restrict__ W,
    const float* __restrict__ bias, void* __restrict__ Cout,
    int K, int Nout, float alpha, int relu, int out_mode)
{
    __shared__ float As[32][68];
    __shared__ float Ws[32][68];
    const int t = threadIdx.x;
    const int ty = t >> 4, tx = t & 15;
    const int rowBase = blockIdx.y * 64;
    const int colBase = blockIdx.x * 64;
    const int lr = t >> 2;
    const int lc = (t & 3) * 8;
    const float* Ap = A + (size_t)(rowBase + lr) * K + lc;
    const float* Wp = W + (size_t)(colBase + lr) * K + lc;
    float acc[4][4] = {{0.f}};
    for (int k0 = 0; k0 < K; k0 += 32) {
        float4 a0 = *(const float4*)(Ap + k0);
        float4 a1 = *(const float4*)(Ap + k0 + 4);
        float4 w0 = *(const float4*)(Wp + k0);
        float4 w1 = *(const float4*)(Wp + k0 + 4);
        __syncthreads();
        As[lc+0][lr]=a0.x; As[lc+1][lr]=a0.y; As[lc+2][lr]=a0.z; As[lc+3][lr]=a0.w;
        As[lc+4][lr]=a1.x; As[lc+5][lr]=a1.y; As[lc+6][lr]=a1.z; As[lc+7][lr]=a1.w;
        Ws[lc+0][lr]=w0.x; Ws[lc+1][lr]=w0.y; Ws[lc+2][lr]=w0.z; Ws[lc+3][lr]=w0.w;
        Ws[lc+4][lr]=w1.x; Ws[lc+5][lr]=w1.y; Ws[lc+6][lr]=w1.z; Ws[lc+7][lr]=w1.w;
        __syncthreads();
        #pragma unroll
        for (int kk = 0; kk < 32; kk++) {
            float4 av = *(const float4*)&As[kk][ty*4];
            float4 wv = *(const float4*)&Ws[kk][tx*4];
            acc[0][0] += av.x*wv.x; acc[0][1] += av.x*wv.y; acc[0][2] += av.x*wv.z; acc[0][3] += av.x*wv.w;
            acc[1][0] += av.y*wv.x; acc[1][1] += av.y*wv.y; acc[1][2] += av.y*wv.z; acc[1][3] += av.y*wv.w;
            acc[2][0] += av.z*wv.x; acc[2][1] += av.z*wv.y; acc[2][2] += av.z*wv.z; acc[2][3] += av.z*wv.w;
            acc[3][0] += av.w*wv.x; acc[3][1] += av.w*wv.y; acc[3][2] += av.w*wv.z; acc[3][3] += av.w*wv.w;
        }
    }
    const int c0 = colBase + tx * 4;
    const float bb[4] = { bias[c0], bias[c0+1], bias[c0+2], bias[c0+3] };
    #pragma unroll
    for (int i = 0; i < 4; i++) {
        float o[4];
        #pragma unroll
        for (int j = 0; j < 4; j++) {
            o[j] = (acc[i][j] + bb[j]) * alpha;
            if (relu) o[j] = fmaxf(o[j], 0.f);
        }
        const int r = rowBase + ty * 4 + i;
        if (out_mode == 0) {
            float4 v = { o[0], o[1], o[2], o[3] };
            *(float4*)&((float*)Cout)[(size_t)r * Nout + c0] = v;
        } else if (out_mode == 1) {
            ushort4 v = { f2bf(o[0]), f2bf(o[1]), f2bf(o[2]), f2bf(o[3]) };
            *(ushort4*)&((ushort*)Cout)[(size_t)r * Nout + c0] = v;
        } else {
            const int bidx = r >> 9, key = r & 511;
            #pragma unroll
            for (int j = 0; j < 4; j++)
                ((ushort*)Cout)[((size_t)(bidx * H + c0 + j)) * NSC + key] = f2bf(o[j]);
        }
    }
}

// Flash-style MFMA cross-attention. Block = 512 threads = 8 waves; wave w =
// head w; 32 queries per block. K staged row-major bf16, V staged transposed
// (from vT global). P does a per-wave LDS round-trip (C-layout -> A-layout).
// Pass 2 recomputes S, normalizes, and sums heads in LDS for attn_score.
__global__ __launch_bounds__(512, 4) void attn_mfma_kernel(
    const ushort* __restrict__ q, const ushort* __restrict__ k,
    const ushort* __restrict__ vt, float* __restrict__ ctx_out,
    float* __restrict__ attn_score)
{
    __shared__ ushort Ks[32 * 264];      // [key][256 d + 8 pad]
    __shared__ ushort Vs[256 * 40];      // [d][32 keys + 8 pad]
    __shared__ ushort Pb[8 * 32 * 40];   // per-wave [32 q][32 keys + 8 pad]
    const int t = threadIdx.x;
    const int w = t >> 6;                // head
    const int lane = t & 63;
    const int g = lane >> 4;             // quad
    const int l15 = lane & 15;
    const int b = blockIdx.x >> 7;
    const int m0 = (blockIdx.x & 127) * 32;

    // Q fragments (A-layout): lane holds Q[m=l15][k=8g..8g+7] per 16-q tile
    bf16x8 qf[2];
    #pragma unroll
    for (int qt = 0; qt < 2; qt++)
        qf[qt] = *(const bf16x8*)&q[((size_t)(b*MQ + m0 + qt*16 + l15)) * H + w*32 + g*8];

    f32x4 cacc[2][2];
    float lacc[2][4];
    #pragma unroll
    for (int qt = 0; qt < 2; qt++) {
        #pragma unroll
        for (int dt = 0; dt < 2; dt++) cacc[qt][dt] = (f32x4){0.f,0.f,0.f,0.f};
        #pragma unroll
        for (int r = 0; r < 4; r++) lacc[qt][r] = 0.f;
    }
    const size_t kg = (size_t)b * NSC * H;
    const size_t vg = (size_t)b * H * NSC;

    // ---- pass 1: l + ctx ----
    for (int c = 0; c < 16; c++) {
        const int kbase = c * 32;
        __syncthreads();
        #pragma unroll
        for (int i = 0; i < 2; i++) {
            int u = t + 512 * i;
            int key = u >> 5, part = u & 31;
            *(bf16x8*)&Ks[key*264 + part*8] =
                *(const bf16x8*)&k[kg + (size_t)(kbase + key)*H + part*8];
            int d = u >> 2, p2 = u & 3;
            *(bf16x8*)&Vs[d*40 + p2*8] =
                *(const bf16x8*)&vt[vg + (size_t)d*NSC + kbase + p2*8];
        }
        __syncthreads();
        #pragma unroll
        for (int qt = 0; qt < 2; qt++) {
            #pragma unroll
            for (int kt = 0; kt < 2; kt++) {
                bf16x8 kf = *(const bf16x8*)&Ks[(kt*16 + l15)*264 + w*32 + g*8];
                f32x4 s = __builtin_amdgcn_mfma_f32_16x16x32_bf16(
                    qf[qt], kf, (f32x4){0.f,0.f,0.f,0.f}, 0, 0, 0);
                #pragma unroll
                for (int r = 0; r < 4; r++) {
                    float p = __expf(s[r]);
                    lacc[qt][r] += p;
                    Pb[(w*32 + qt*16 + g*4 + r)*40 + kt*16 + l15] = f2bf(p);
                }
            }
        }
        // PV: A = P (LDS round-trip), B = Vt
        #pragma unroll
        for (int qt = 0; qt < 2; qt++) {
            bf16x8 pf = *(const bf16x8*)&Pb[(w*32 + qt*16 + l15)*40 + g*8];
            #pragma unroll
            for (int dt = 0; dt < 2; dt++) {
                bf16x8 vf = *(const bf16x8*)&Vs[(w*32 + dt*16 + l15)*40 + g*8];
                cacc[qt][dt] = __builtin_amdgcn_mfma_f32_16x16x32_bf16(
                    pf, vf, cacc[qt][dt], 0, 0, 0);
            }
        }
    }

    // reduce l across the 16 cols (lanes sharing g), scale + store ctx
    float invl[2][4];
    #pragma unroll
    for (int qt = 0; qt < 2; qt++)
        #pragma unroll
        for (int r = 0; r < 4; r++) {
            float v = lacc[qt][r];
            v += __shfl_xor(v, 1); v += __shfl_xor(v, 2);
            v += __shfl_xor(v, 4); v += __shfl_xor(v, 8);
            invl[qt][r] = 1.f / v;
        }
    #pragma unroll
    for (int qt = 0; qt < 2; qt++)
        #pragma unroll
        for (int dt = 0; dt < 2; dt++)
            #pragma unroll
            for (int r = 0; r < 4; r++)
                ctx_out[((size_t)(b*MQ + m0 + qt*16 + g*4 + r))*H + w*32 + dt*16 + l15]
                    = cacc[qt][dt][r] * invl[qt][r];

    // ---- pass 2: attn_score = mean over heads of normalized P ----
    for (int c = 0; c < 16; c++) {
        const int kbase = c * 32;
        __syncthreads();
        #pragma unroll
        for (int i = 0; i < 2; i++) {
            int u = t + 512 * i;
            int key = u >> 5, part = u & 31;
            *(bf16x8*)&Ks[key*264 + part*8] =
                *(const bf16x8*)&k[kg + (size_t)(kbase + key)*H + part*8];
        }
        __syncthreads();
        #pragma unroll
        for (int qt = 0; qt < 2; qt++) {
            #pragma unroll
            for (int kt = 0; kt < 2; kt++) {
                bf16x8 kf = *(const bf16x8*)&Ks[(kt*16 + l15)*264 + w*32 + g*8];
                f32x4 s = __builtin_amdgcn_mfma_f32_16x16x32_bf16(
                    qf[qt], kf, (f32x4){0.f,0.f,0.f,0.f}, 0, 0, 0);
                #pragma unroll
                for (int r = 0; r < 4; r++) {
                    float p = __expf(s[r]) * invl[qt][r] * 0.125f;
                    Pb[(w*32 + qt*16 + g*4 + r)*40 + kt*16 + l15] = f2bf(p);
                }
            }
        }
        __syncthreads();   // cross-wave Pb reads below
        {
            const int r = t >> 4;
            const int c2 = (t & 15) * 2;
            float v0 = 0.f, v1 = 0.f;
            #pragma unroll
            for (int wv = 0; wv < 8; wv++) {
                v0 += bf2f(Pb[(wv*32 + r)*40 + c2]);
                v1 += bf2f(Pb[(wv*32 + r)*40 + c2 + 1]);
            }
            float2 o = { v0, v1 };
            *(float2*)&attn_score[((size_t)(b*MQ + m0 + r))*NSC + kbase + c2] = o;
        }
    }
}

// out = LN(a + bres) * g + beta, rows of H=256, one row per block
__global__ __launch_bounds__(256) void add_ln_kernel(
    const float* __restrict__ a, const float* __restrict__ bres,
    const float* __restrict__ g, const float* __restrict__ beta,
    float* __restrict__ out)
{
    __shared__ float red[8];
    const int r = blockIdx.x, t = threadIdx.x;
    float vv = a[(size_t)r*H + t] + bres[(size_t)r*H + t];
    float s = vv;
    #pragma unroll
    for (int o = 32; o > 0; o >>= 1) s += __shfl_down(s, o, 64);
    __syncthreads();
    if ((t & 63) == 0) red[t >> 6] = s;
    __syncthreads();
    float mu = (red[0] + red[1] + red[2] + red[3]) * (1.f / 256.f);
    float d = vv - mu;
    float s2 = d * d;
    #pragma unroll
    for (int o = 32; o > 0; o >>= 1) s2 += __shfl_down(s2, o, 64);
    __syncthreads();
    if ((t & 63) == 0) red[t >> 6] = s2;
    __syncthreads();
    float var = (red[0] + red[1] + red[2] + red[3]) * (1.f / 256.f);
    out[(size_t)r*H + t] = d * rsqrtf(var + 1e-6f) * g[t] + beta[t];
}

extern "C" void kernel_launch(void* const* d_in, const int* in_sizes, int n_in,
                              void* d_out, int out_size, void* d_ws, size_t ws_size,
                              hipStream_t stream)
{
    const float* hidden = (const float*)d_in[0];
    const float* scene  = (const float*)d_in[1];
    const float* in_w   = (const float*)d_in[2];
    const float* in_b   = (const float*)d_in[3];
    const float* out_w  = (const float*)d_in[4];
    const float* out_b  = (const float*)d_in[5];
    const float* aln_g  = (const float*)d_in[6];
    const float* aln_b  = (const float*)d_in[7];
    const float* ff1_w  = (const float*)d_in[8];
    const float* ff1_b  = (const float*)d_in[9];
    const float* ff2_w  = (const float*)d_in[10];
    const float* ff2_b  = (const float*)d_in[11];
    const float* fln_g  = (const float*)d_in[12];
    const float* fln_b  = (const float*)d_in[13];

    float* out0  = (float*)d_out;
    float* score = out0 + (size_t)BATCH * MQ * H;

    ushort* qb  = (ushort*)d_ws;                               // 16384x256 bf16
    ushort* kb  = qb  + (size_t)BATCH * MQ  * H;               // 2048x256 bf16
    ushort* vtb = kb  + (size_t)BATCH * NSC * H;               // [b][256][512] bf16
    float*  ctx = (float*)(vtb + (size_t)BATCH * H * NSC);     // 16384x256 f32
    float*  att = ctx + (size_t)BATCH * MQ * H;                // 16384x256 f32
    float*  xb  = att + (size_t)BATCH * MQ * H;                // 16384x256 f32
    float*  fb  = xb  + (size_t)BATCH * MQ * H;                // 16384x128 f32

    const float scale = 0.17677669529663687f;                  // 1/sqrt(32)
    dim3 blk(256);

    // q = bf16((hidden @ Wq^T + bq) * scale)
    gemm_bias_kernel<<<dim3(4, 256), blk, 0, stream>>>(hidden, in_w,           in_b,       qb,  256, 256, scale, 0, 1);
    // k = bf16(scene @ Wk^T + bk) row-major
    gemm_bias_kernel<<<dim3(4, 32),  blk, 0, stream>>>(scene,  in_w + 256*256, in_b + 256, kb,  256, 256, 1.f,   0, 1);
    // vT = bf16(scene @ Wv^T + bv) transposed per batch
    gemm_bias_kernel<<<dim3(4, 32),  blk, 0, stream>>>(scene,  in_w + 512*256, in_b + 512, vtb, 256, 256, 1.f,   0, 2);
    // fused MFMA attention -> ctx (f32) + attn_score
    attn_mfma_kernel<<<dim3(512), dim3(512), 0, stream>>>(qb, kb, vtb, ctx, score);
    // attn_out = ctx @ Wout^T + bout
    gemm_bias_kernel<<<dim3(4, 256), blk, 0, stream>>>(ctx, out_w, out_b, att, 256, 256, 1.f, 0, 0);
    // x = LN(attn_out + hidden)
    add_ln_kernel<<<dim3(16384), blk, 0, stream>>>(att, hidden, aln_g, aln_b, xb);
    // f = relu(x @ W1^T + b1)
    gemm_bias_kernel<<<dim3(2, 256), blk, 0, stream>>>(xb, ff1_w, ff1_b, fb, 256, 128, 1.f, 1, 0);
    // y = f @ W2^T + b2
    gemm_bias_kernel<<<dim3(4, 256), blk, 0, stream>>>(fb, ff2_w, ff2_b, ctx, 128, 256, 1.f, 0, 0);
    // out = LN(y + x)
    add_ln_kernel<<<dim3(16384), blk, 0, stream>>>(ctx, xb, fln_g, fln_b, out0);
}

// Round 3
// 289.524 us; speedup vs baseline: 2.9154x; 1.0650x over previous
//
#include <hip/hip_runtime.h>
#include <hip/hip_bf16.h>

#define H 256
#define NSC 512
#define MQ 4096
#define BATCH 4

typedef __attribute__((ext_vector_type(8))) short bf16x8;
typedef __attribute__((ext_vector_type(4))) float f32x4;
typedef __attribute__((ext_vector_type(8))) unsigned short ushort8;

__device__ __forceinline__ ushort f2bf(float x) {
    union { float f; unsigned u; } c; c.f = x;
    unsigned r = c.u + 0x7FFF + ((c.u >> 16) & 1);   // RNE
    return (ushort)(r >> 16);
}
__device__ __forceinline__ float bf2f(ushort u) {
    union { unsigned u; float f; } c; c.u = ((unsigned)u) << 16;
    return c.f;
}

// ---- f32 -> bf16 bulk convert, 6 tensors in one launch (blockIdx.y = slot) ----
struct CvtArgs {
    const float* src[6];
    ushort* dst[6];
    int n[6];
};
__global__ __launch_bounds__(256) void cvt_kernel(CvtArgs a) {
    const int s = blockIdx.y;
    const int i = (blockIdx.x * 256 + threadIdx.x) * 8;
    if (i >= a.n[s]) return;
    const float* sp = a.src[s] + i;
    float4 v0 = *(const float4*)sp;
    float4 v1 = *(const float4*)(sp + 4);
    ushort8 o;
    o[0]=f2bf(v0.x); o[1]=f2bf(v0.y); o[2]=f2bf(v0.z); o[3]=f2bf(v0.w);
    o[4]=f2bf(v1.x); o[5]=f2bf(v1.y); o[6]=f2bf(v1.z); o[7]=f2bf(v1.w);
    *(ushort8*)(a.dst[s] + i) = o;
}

// ---- bf16 MFMA GEMM: D[M,N] = act((A[M,K] @ W[N,K]^T + bias[col]) * alpha)
// 128x128 tile, BK=64, 4 waves in 2x2, each 64x64 via 16x16x32 mfma.
// LDS: [row][64 ushorts], 16B chunk position XOR-swizzled (p = kc ^ (row&7))
// so fragment ds_read_b128 is 2-way (free) and staging stores are full-spread.
// mode: 0 = f32 row-major, 1 = bf16 row-major,
//       2 = bf16 transposed per 512-row batch: out[(row>>9)*256 + col][row&511]
__global__ __launch_bounds__(256) void gemm_bf16_kernel(
    const ushort* __restrict__ A, const ushort* __restrict__ W,
    const float* __restrict__ bias, void* __restrict__ out,
    int K, int N, float alpha, int relu, int mode)
{
    __shared__ ushort As[128 * 64];
    __shared__ ushort Bs[128 * 64];
    const int t = threadIdx.x;
    const int wv = t >> 6, lane = t & 63, g = lane >> 4, l15 = lane & 15;
    const int rowBase = blockIdx.y * 128, colBase = blockIdx.x * 128;
    const int wr = (wv >> 1) * 64, wc = (wv & 1) * 64;
    f32x4 acc[4][4];
    #pragma unroll
    for (int mi = 0; mi < 4; mi++)
        #pragma unroll
        for (int ni = 0; ni < 4; ni++) acc[mi][ni] = (f32x4){0.f,0.f,0.f,0.f};

    for (int k0 = 0; k0 < K; k0 += 64) {
        uint4 av[4], wv4[4];
        #pragma unroll
        for (int i = 0; i < 4; i++) {
            const int u = t + 256*i, row = u >> 3, kc = u & 7;
            av[i]  = *(const uint4*)&A[(size_t)(rowBase + row) * K + k0 + kc*8];
            wv4[i] = *(const uint4*)&W[(size_t)(colBase + row) * K + k0 + kc*8];
        }
        __syncthreads();
        #pragma unroll
        for (int i = 0; i < 4; i++) {
            const int u = t + 256*i, row = u >> 3, kc = u & 7, p = kc ^ (row & 7);
            *(uint4*)&As[row*64 + p*8] = av[i];
            *(uint4*)&Bs[row*64 + p*8] = wv4[i];
        }
        __syncthreads();
        #pragma unroll
        for (int kk = 0; kk < 2; kk++) {
            const int swz = ((kk*4 + g) ^ (l15 & 7)) * 8;
            bf16x8 af[4], bfr[4];
            #pragma unroll
            for (int mi = 0; mi < 4; mi++)
                af[mi] = *(const bf16x8*)&As[(wr + mi*16 + l15)*64 + swz];
            #pragma unroll
            for (int ni = 0; ni < 4; ni++)
                bfr[ni] = *(const bf16x8*)&Bs[(wc + ni*16 + l15)*64 + swz];
            #pragma unroll
            for (int mi = 0; mi < 4; mi++)
                #pragma unroll
                for (int ni = 0; ni < 4; ni++)
                    acc[mi][ni] = __builtin_amdgcn_mfma_f32_16x16x32_bf16(
                        af[mi], bfr[ni], acc[mi][ni], 0, 0, 0);
        }
    }

    #pragma unroll
    for (int ni = 0; ni < 4; ni++) {
        const int col = colBase + wc + ni*16 + l15;
        const float bb = bias[col];
        #pragma unroll
        for (int mi = 0; mi < 4; mi++) {
            const int row = rowBase + wr + mi*16 + g*4;
            float o[4];
            #pragma unroll
            for (int r = 0; r < 4; r++) {
                o[r] = (acc[mi][ni][r] + bb) * alpha;
                if (relu) o[r] = fmaxf(o[r], 0.f);
            }
            if (mode == 0) {
                #pragma unroll
                for (int r = 0; r < 4; r++)
                    ((float*)out)[(size_t)(row + r) * N + col] = o[r];
            } else if (mode == 1) {
                #pragma unroll
                for (int r = 0; r < 4; r++)
                    ((ushort*)out)[(size_t)(row + r) * N + col] = f2bf(o[r]);
            } else {
                const int bidx = row >> 9, key = row & 511;
                ushort4 pk = { f2bf(o[0]), f2bf(o[1]), f2bf(o[2]), f2bf(o[3]) };
                *(ushort4*)&((ushort*)out)[(size_t)(bidx*H + col) * NSC + key] = pk;
            }
        }
    }
}

// ---- Flash-style MFMA cross-attention (unchanged structure from R2, but
// writes ctx as bf16 so out_proj consumes it directly). ----
__global__ __launch_bounds__(512, 4) void attn_mfma_kernel(
    const ushort* __restrict__ q, const ushort* __restrict__ k,
    const ushort* __restrict__ vt, ushort* __restrict__ ctx_out,
    float* __restrict__ attn_score)
{
    __shared__ ushort Ks[32 * 264];
    __shared__ ushort Vs[256 * 40];
    __shared__ ushort Pb[8 * 32 * 40];
    const int t = threadIdx.x;
    const int w = t >> 6;
    const int lane = t & 63;
    const int g = lane >> 4;
    const int l15 = lane & 15;
    const int b = blockIdx.x >> 7;
    const int m0 = (blockIdx.x & 127) * 32;

    bf16x8 qf[2];
    #pragma unroll
    for (int qt = 0; qt < 2; qt++)
        qf[qt] = *(const bf16x8*)&q[((size_t)(b*MQ + m0 + qt*16 + l15)) * H + w*32 + g*8];

    f32x4 cacc[2][2];
    float lacc[2][4];
    #pragma unroll
    for (int qt = 0; qt < 2; qt++) {
        #pragma unroll
        for (int dt = 0; dt < 2; dt++) cacc[qt][dt] = (f32x4){0.f,0.f,0.f,0.f};
        #pragma unroll
        for (int r = 0; r < 4; r++) lacc[qt][r] = 0.f;
    }
    const size_t kg = (size_t)b * NSC * H;
    const size_t vg = (size_t)b * H * NSC;

    for (int c = 0; c < 16; c++) {
        const int kbase = c * 32;
        __syncthreads();
        #pragma unroll
        for (int i = 0; i < 2; i++) {
            int u = t + 512 * i;
            int key = u >> 5, part = u & 31;
            *(bf16x8*)&Ks[key*264 + part*8] =
                *(const bf16x8*)&k[kg + (size_t)(kbase + key)*H + part*8];
            int d = u >> 2, p2 = u & 3;
            *(bf16x8*)&Vs[d*40 + p2*8] =
                *(const bf16x8*)&vt[vg + (size_t)d*NSC + kbase + p2*8];
        }
        __syncthreads();
        #pragma unroll
        for (int qt = 0; qt < 2; qt++) {
            #pragma unroll
            for (int kt = 0; kt < 2; kt++) {
                bf16x8 kf = *(const bf16x8*)&Ks[(kt*16 + l15)*264 + w*32 + g*8];
                f32x4 s = __builtin_amdgcn_mfma_f32_16x16x32_bf16(
                    qf[qt], kf, (f32x4){0.f,0.f,0.f,0.f}, 0, 0, 0);
                #pragma unroll
                for (int r = 0; r < 4; r++) {
                    float p = __expf(s[r]);
                    lacc[qt][r] += p;
                    Pb[(w*32 + qt*16 + g*4 + r)*40 + kt*16 + l15] = f2bf(p);
                }
            }
        }
        #pragma unroll
        for (int qt = 0; qt < 2; qt++) {
            bf16x8 pf = *(const bf16x8*)&Pb[(w*32 + qt*16 + l15)*40 + g*8];
            #pragma unroll
            for (int dt = 0; dt < 2; dt++) {
                bf16x8 vf = *(const bf16x8*)&Vs[(w*32 + dt*16 + l15)*40 + g*8];
                cacc[qt][dt] = __builtin_amdgcn_mfma_f32_16x16x32_bf16(
                    pf, vf, cacc[qt][dt], 0, 0, 0);
            }
        }
    }

    float invl[2][4];
    #pragma unroll
    for (int qt = 0; qt < 2; qt++)
        #pragma unroll
        for (int r = 0; r < 4; r++) {
            float v = lacc[qt][r];
            v += __shfl_xor(v, 1); v += __shfl_xor(v, 2);
            v += __shfl_xor(v, 4); v += __shfl_xor(v, 8);
            invl[qt][r] = 1.f / v;
        }
    #pragma unroll
    for (int qt = 0; qt < 2; qt++)
        #pragma unroll
        for (int dt = 0; dt < 2; dt++)
            #pragma unroll
            for (int r = 0; r < 4; r++)
                ctx_out[((size_t)(b*MQ + m0 + qt*16 + g*4 + r))*H + w*32 + dt*16 + l15]
                    = f2bf(cacc[qt][dt][r] * invl[qt][r]);

    for (int c = 0; c < 16; c++) {
        const int kbase = c * 32;
        __syncthreads();
        #pragma unroll
        for (int i = 0; i < 2; i++) {
            int u = t + 512 * i;
            int key = u >> 5, part = u & 31;
            *(bf16x8*)&Ks[key*264 + part*8] =
                *(const bf16x8*)&k[kg + (size_t)(kbase + key)*H + part*8];
        }
        __syncthreads();
        #pragma unroll
        for (int qt = 0; qt < 2; qt++) {
            #pragma unroll
            for (int kt = 0; kt < 2; kt++) {
                bf16x8 kf = *(const bf16x8*)&Ks[(kt*16 + l15)*264 + w*32 + g*8];
                f32x4 s = __builtin_amdgcn_mfma_f32_16x16x32_bf16(
                    qf[qt], kf, (f32x4){0.f,0.f,0.f,0.f}, 0, 0, 0);
                #pragma unroll
                for (int r = 0; r < 4; r++) {
                    float p = __expf(s[r]) * invl[qt][r] * 0.125f;
                    Pb[(w*32 + qt*16 + g*4 + r)*40 + kt*16 + l15] = f2bf(p);
                }
            }
        }
        __syncthreads();
        {
            const int r = t >> 4;
            const int c2 = (t & 15) * 2;
            float v0 = 0.f, v1 = 0.f;
            #pragma unroll
            for (int wvi = 0; wvi < 8; wvi++) {
                v0 += bf2f(Pb[(wvi*32 + r)*40 + c2]);
                v1 += bf2f(Pb[(wvi*32 + r)*40 + c2 + 1]);
            }
            float2 o = { v0, v1 };
            *(float2*)&attn_score[((size_t)(b*MQ + m0 + r))*NSC + kbase + c2] = o;
        }
    }
}

// out = LN(a + bres) * g + beta; optional bf16 copy of the output
__global__ __launch_bounds__(256) void add_ln_kernel(
    const float* __restrict__ a, const float* __restrict__ bres,
    const float* __restrict__ g, const float* __restrict__ beta,
    float* __restrict__ out, ushort* __restrict__ out_bf)
{
    __shared__ float red[8];
    const int r = blockIdx.x, t = threadIdx.x;
    float vv = a[(size_t)r*H + t] + bres[(size_t)r*H + t];
    float s = vv;
    #pragma unroll
    for (int o = 32; o > 0; o >>= 1) s += __shfl_down(s, o, 64);
    __syncthreads();
    if ((t & 63) == 0) red[t >> 6] = s;
    __syncthreads();
    float mu = (red[0] + red[1] + red[2] + red[3]) * (1.f / 256.f);
    float d = vv - mu;
    float s2 = d * d;
    #pragma unroll
    for (int o = 32; o > 0; o >>= 1) s2 += __shfl_down(s2, o, 64);
    __syncthreads();
    if ((t & 63) == 0) red[t >> 6] = s2;
    __syncthreads();
    float var = (red[0] + red[1] + red[2] + red[3]) * (1.f / 256.f);
    float o = d * rsqrtf(var + 1e-6f) * g[t] + beta[t];
    out[(size_t)r*H + t] = o;
    if (out_bf) out_bf[(size_t)r*H + t] = f2bf(o);
}

extern "C" void kernel_launch(void* const* d_in, const int* in_sizes, int n_in,
                              void* d_out, int out_size, void* d_ws, size_t ws_size,
                              hipStream_t stream)
{
    const float* hidden = (const float*)d_in[0];
    const float* scene  = (const float*)d_in[1];
    const float* in_w   = (const float*)d_in[2];
    const float* in_b   = (const float*)d_in[3];
    const float* out_w  = (const float*)d_in[4];
    const float* out_b  = (const float*)d_in[5];
    const float* aln_g  = (const float*)d_in[6];
    const float* aln_b  = (const float*)d_in[7];
    const float* ff1_w  = (const float*)d_in[8];
    const float* ff1_b  = (const float*)d_in[9];
    const float* ff2_w  = (const float*)d_in[10];
    const float* ff2_b  = (const float*)d_in[11];
    const float* fln_g  = (const float*)d_in[12];
    const float* fln_b  = (const float*)d_in[13];

    float* out0  = (float*)d_out;
    float* score = out0 + (size_t)BATCH * MQ * H;

    ushort* hbf  = (ushort*)d_ws;                    // 16384x256
    ushort* sbf  = hbf  + 4194304;                   // 2048x256
    ushort* wqkv = sbf  + 524288;                    // 768x256
    ushort* wo   = wqkv + 196608;                    // 256x256
    ushort* w1   = wo   + 65536;                     // 128x256
    ushort* w2   = w1   + 32768;                     // 256x128
    ushort* qb   = w2   + 32768;                     // 16384x256
    ushort* kb   = qb   + 4194304;                   // 2048x256
    ushort* vtb  = kb   + 524288;                    // [b][256][512]
    ushort* ctxb = vtb  + 524288;                    // 16384x256
    ushort* xbh  = ctxb + 4194304;                   // 16384x256
    ushort* fb   = xbh  + 4194304;                   // 16384x128
    float*  att  = (float*)(fb + 2097152);           // 16384x256 f32 (also y)
    float*  xb   = att + 4194304;                    // 16384x256 f32

    const float scale = 0.17677669529663687f;        // 1/sqrt(32)

    CvtArgs ca;
    ca.src[0]=hidden; ca.dst[0]=hbf;  ca.n[0]=4194304;
    ca.src[1]=scene;  ca.dst[1]=sbf;  ca.n[1]=524288;
    ca.src[2]=in_w;   ca.dst[2]=wqkv; ca.n[2]=196608;
    ca.src[3]=out_w;  ca.dst[3]=wo;   ca.n[3]=65536;
    ca.src[4]=ff1_w;  ca.dst[4]=w1;   ca.n[4]=32768;
    ca.src[5]=ff2_w;  ca.dst[5]=w2;   ca.n[5]=32768;
    cvt_kernel<<<dim3(2048, 6), dim3(256), 0, stream>>>(ca);

    // q = bf16((hidden @ Wq^T + bq) * scale)
    gemm_bf16_kernel<<<dim3(2, 128), dim3(256), 0, stream>>>(
        hbf, wqkv, in_b, qb, 256, 256, scale, 0, 1);
    // k = bf16(scene @ Wk^T + bk)
    gemm_bf16_kernel<<<dim3(2, 16), dim3(256), 0, stream>>>(
        sbf, wqkv + 65536, in_b + 256, kb, 256, 256, 1.f, 0, 1);
    // vT = bf16(scene @ Wv^T + bv), transposed per batch
    gemm_bf16_kernel<<<dim3(2, 16), dim3(256), 0, stream>>>(
        sbf, wqkv + 131072, in_b + 512, vtb, 256, 256, 1.f, 0, 2);
    // fused MFMA attention -> ctx (bf16) + attn_score
    attn_mfma_kernel<<<dim3(512), dim3(512), 0, stream>>>(qb, kb, vtb, ctxb, score);
    // attn_out = ctx @ Wout^T + bout  (f32)
    gemm_bf16_kernel<<<dim3(2, 128), dim3(256), 0, stream>>>(
        ctxb, wo, out_b, att, 256, 256, 1.f, 0, 0);
    // x = LN(attn_out + hidden)  (f32 + bf16)
    add_ln_kernel<<<dim3(16384), dim3(256), 0, stream>>>(att, hidden, aln_g, aln_b, xb, xbh);
    // f = bf16(relu(x @ W1^T + b1))
    gemm_bf16_kernel<<<dim3(1, 128), dim3(256), 0, stream>>>(
        xbh, w1, ff1_b, fb, 256, 128, 1.f, 1, 1);
    // y = f @ W2^T + b2  (f32, reuse att)
    gemm_bf16_kernel<<<dim3(2, 128), dim3(256), 0, stream>>>(
        fb, w2, ff2_b, att, 128, 256, 1.f, 0, 0);
    // out = LN(y + x)
    add_ln_kernel<<<dim3(16384), dim3(256), 0, stream>>>(att, xb, fln_g, fln_b, out0, (ushort*)0);
}

// Round 4
// 284.624 us; speedup vs baseline: 2.9655x; 1.0172x over previous
//
#include <hip/hip_runtime.h>
#include <hip/hip_bf16.h>

#define H 256
#define NSC 512
#define MQ 4096
#define BATCH 4

typedef __attribute__((ext_vector_type(8))) short bf16x8;
typedef __attribute__((ext_vector_type(4))) float f32x4;
typedef __attribute__((ext_vector_type(8))) unsigned short ushort8;

__device__ __forceinline__ ushort f2bf(float x) {
    union { float f; unsigned u; } c; c.f = x;
    unsigned r = c.u + 0x7FFF + ((c.u >> 16) & 1);   // RNE
    return (ushort)(r >> 16);
}
__device__ __forceinline__ float bf2f(ushort u) {
    union { unsigned u; float f; } c; c.u = ((unsigned)u) << 16;
    return c.f;
}

// ---- f32 -> bf16 bulk convert, 6 tensors in one launch ----
struct CvtArgs {
    const float* src[6];
    ushort* dst[6];
    int n[6];
};
__global__ __launch_bounds__(256) void cvt_kernel(CvtArgs a) {
    const int s = blockIdx.y;
    const int i = (blockIdx.x * 256 + threadIdx.x) * 8;
    if (i >= a.n[s]) return;
    const float* sp = a.src[s] + i;
    float4 v0 = *(const float4*)sp;
    float4 v1 = *(const float4*)(sp + 4);
    ushort8 o;
    o[0]=f2bf(v0.x); o[1]=f2bf(v0.y); o[2]=f2bf(v0.z); o[3]=f2bf(v0.w);
    o[4]=f2bf(v1.x); o[5]=f2bf(v1.y); o[6]=f2bf(v1.z); o[7]=f2bf(v1.w);
    *(ushort8*)(a.dst[s] + i) = o;
}

// ---- bf16 MFMA GEMM: D = act((A[M,K] @ W[N,K]^T + bias[col]) * alpha)
// mode 0: f32 row-major to out. mode 1: bf16 row-major to out.
// mode 3: col<256 -> bf16 row-major (stride 256) to out (k);
//         col>=256 -> bf16 transposed per 512-row batch to out2 (vT):
//         out2[(row>>9)*256 + (col-256)][row&511]
__global__ __launch_bounds__(256) void gemm_bf16_kernel(
    const ushort* __restrict__ A, const ushort* __restrict__ W,
    const float* __restrict__ bias, void* __restrict__ out,
    ushort* __restrict__ out2, int K, int N, float alpha, int relu, int mode)
{
    __shared__ ushort As[128 * 64];
    __shared__ ushort Bs[128 * 64];
    const int t = threadIdx.x;
    const int wv = t >> 6, lane = t & 63, g = lane >> 4, l15 = lane & 15;
    const int rowBase = blockIdx.y * 128, colBase = blockIdx.x * 128;
    const int wr = (wv >> 1) * 64, wc = (wv & 1) * 64;
    f32x4 acc[4][4];
    #pragma unroll
    for (int mi = 0; mi < 4; mi++)
        #pragma unroll
        for (int ni = 0; ni < 4; ni++) acc[mi][ni] = (f32x4){0.f,0.f,0.f,0.f};

    for (int k0 = 0; k0 < K; k0 += 64) {
        uint4 av[4], wv4[4];
        #pragma unroll
        for (int i = 0; i < 4; i++) {
            const int u = t + 256*i, row = u >> 3, kc = u & 7;
            av[i]  = *(const uint4*)&A[(size_t)(rowBase + row) * K + k0 + kc*8];
            wv4[i] = *(const uint4*)&W[(size_t)(colBase + row) * K + k0 + kc*8];
        }
        __syncthreads();
        #pragma unroll
        for (int i = 0; i < 4; i++) {
            const int u = t + 256*i, row = u >> 3, kc = u & 7, p = kc ^ (row & 7);
            *(uint4*)&As[row*64 + p*8] = av[i];
            *(uint4*)&Bs[row*64 + p*8] = wv4[i];
        }
        __syncthreads();
        #pragma unroll
        for (int kk = 0; kk < 2; kk++) {
            const int swz = ((kk*4 + g) ^ (l15 & 7)) * 8;
            bf16x8 af[4], bfr[4];
            #pragma unroll
            for (int mi = 0; mi < 4; mi++)
                af[mi] = *(const bf16x8*)&As[(wr + mi*16 + l15)*64 + swz];
            #pragma unroll
            for (int ni = 0; ni < 4; ni++)
                bfr[ni] = *(const bf16x8*)&Bs[(wc + ni*16 + l15)*64 + swz];
            #pragma unroll
            for (int mi = 0; mi < 4; mi++)
                #pragma unroll
                for (int ni = 0; ni < 4; ni++)
                    acc[mi][ni] = __builtin_amdgcn_mfma_f32_16x16x32_bf16(
                        af[mi], bfr[ni], acc[mi][ni], 0, 0, 0);
        }
    }

    #pragma unroll
    for (int ni = 0; ni < 4; ni++) {
        const int col = colBase + wc + ni*16 + l15;
        const float bb = bias[col];
        #pragma unroll
        for (int mi = 0; mi < 4; mi++) {
            const int row = rowBase + wr + mi*16 + g*4;
            float o[4];
            #pragma unroll
            for (int r = 0; r < 4; r++) {
                o[r] = (acc[mi][ni][r] + bb) * alpha;
                if (relu) o[r] = fmaxf(o[r], 0.f);
            }
            if (mode == 0) {
                #pragma unroll
                for (int r = 0; r < 4; r++)
                    ((float*)out)[(size_t)(row + r) * N + col] = o[r];
            } else if (mode == 1) {
                #pragma unroll
                for (int r = 0; r < 4; r++)
                    ((ushort*)out)[(size_t)(row + r) * N + col] = f2bf(o[r]);
            } else {
                if (col < 256) {
                    #pragma unroll
                    for (int r = 0; r < 4; r++)
                        ((ushort*)out)[(size_t)(row + r) * 256 + col] = f2bf(o[r]);
                } else {
                    const int bidx = row >> 9, key = row & 511;
                    ushort4 pk = { f2bf(o[0]), f2bf(o[1]), f2bf(o[2]), f2bf(o[3]) };
                    *(ushort4*)&out2[(size_t)(bidx*H + col - 256) * NSC + key] = pk;
                }
            }
        }
    }
}

// ---- Flash MFMA cross-attention, S^T formulation.
// Block = 512 thr = 8 waves (wave=head), 16 queries/block, grid 1024 (4/CU).
// QK: mfma(A=K, B=Q) -> C[row=key g*4+r][col=q l15]: 4 consecutive keys per
// lane -> pack 2x uint -> one ds_write_b64; A-frag for PV via ds_read_b128.
// K fragments loaded directly from global (L2-hot), no K staging.
__global__ __launch_bounds__(512, 8) void attn_mfma_kernel(
    const ushort* __restrict__ q, const ushort* __restrict__ k,
    const ushort* __restrict__ vt, ushort* __restrict__ ctx_out,
    float* __restrict__ attn_score)
{
    __shared__ ushort Vs[256 * 40];      // [d][32 keys + 8 pad]
    __shared__ ushort Ps[8 * 16 * 40];   // per-wave [16 q][32 keys + 8 pad]
    const int t = threadIdx.x;
    const int w = t >> 6;                // head
    const int lane = t & 63;
    const int g = lane >> 4;
    const int l15 = lane & 15;
    const int b = blockIdx.x >> 8;
    const int m0 = (blockIdx.x & 255) * 16;

    // Q B-fragment: lane holds Q[q=m0+l15][d = w*32 + g*8 .. +7]
    const bf16x8 qf = *(const bf16x8*)&q[((size_t)(b*MQ + m0 + l15)) * H + w*32 + g*8];

    const size_t kg = (size_t)b * NSC * H;
    const size_t vg = (size_t)b * H * NSC;
    const int prow = (w*16 + l15) * 40;          // this lane's Ps row (ushorts)

    f32x4 cacc[2];
    cacc[0] = (f32x4){0.f,0.f,0.f,0.f};
    cacc[1] = (f32x4){0.f,0.f,0.f,0.f};
    float lacc = 0.f;

    // ---- pass 1: denominators + ctx ----
    for (int c = 0; c < 16; c++) {
        const int kbase = c * 32;
        __syncthreads();
        #pragma unroll
        for (int i = 0; i < 2; i++) {
            int u = t + 512 * i;
            int d = u >> 2, p2 = u & 3;
            *(bf16x8*)&Vs[d*40 + p2*8] =
                *(const bf16x8*)&vt[vg + (size_t)d*NSC + kbase + p2*8];
        }
        __syncthreads();
        #pragma unroll
        for (int kt = 0; kt < 2; kt++) {
            bf16x8 kf = *(const bf16x8*)&k[kg + (size_t)(kbase + kt*16 + l15)*H + w*32 + g*8];
            f32x4 s = __builtin_amdgcn_mfma_f32_16x16x32_bf16(
                kf, qf, (f32x4){0.f,0.f,0.f,0.f}, 0, 0, 0);
            float e0 = __expf(s[0]), e1 = __expf(s[1]);
            float e2 = __expf(s[2]), e3 = __expf(s[3]);
            lacc += (e0 + e1) + (e2 + e3);
            uint2 pk;
            pk.x = (unsigned)f2bf(e0) | ((unsigned)f2bf(e1) << 16);
            pk.y = (unsigned)f2bf(e2) | ((unsigned)f2bf(e3) << 16);
            *(uint2*)&Ps[prow + kt*16 + g*4] = pk;
        }
        // PV: A = P[q=l15][key g*8..+7], B = V^T[d][key]
        bf16x8 pf = *(const bf16x8*)&Ps[prow + g*8];
        #pragma unroll
        for (int dt = 0; dt < 2; dt++) {
            bf16x8 vf = *(const bf16x8*)&Vs[(w*32 + dt*16 + l15)*40 + g*8];
            cacc[dt] = __builtin_amdgcn_mfma_f32_16x16x32_bf16(pf, vf, cacc[dt], 0, 0, 0);
        }
    }

    // denominator: sum over g groups (same l15)
    float lsum = lacc;
    lsum += __shfl_xor(lsum, 16);
    lsum += __shfl_xor(lsum, 32);
    const float invl = 1.f / lsum;       // for q = l15

    // ctx rows are q = g*4+r -> fetch those queries' invl
    float invl_r[4];
    #pragma unroll
    for (int r = 0; r < 4; r++) invl_r[r] = __shfl(invl, g*4 + r);
    #pragma unroll
    for (int dt = 0; dt < 2; dt++)
        #pragma unroll
        for (int r = 0; r < 4; r++)
            ctx_out[((size_t)(b*MQ + m0 + g*4 + r))*H + w*32 + dt*16 + l15]
                = f2bf(cacc[dt][r] * invl_r[r]);

    // ---- pass 2: attn_score = mean over heads of normalized P ----
    const float nscale = invl * 0.125f;
    const int q2 = t >> 5;               // 0..15
    const int key2 = t & 31;
    float* srow = &attn_score[((size_t)(b*MQ + m0 + q2))*NSC + key2];
    for (int c = 0; c < 16; c++) {
        const int kbase = c * 32;
        #pragma unroll
        for (int kt = 0; kt < 2; kt++) {
            bf16x8 kf = *(const bf16x8*)&k[kg + (size_t)(kbase + kt*16 + l15)*H + w*32 + g*8];
            f32x4 s = __builtin_amdgcn_mfma_f32_16x16x32_bf16(
                kf, qf, (f32x4){0.f,0.f,0.f,0.f}, 0, 0, 0);
            float e0 = __expf(s[0]) * nscale, e1 = __expf(s[1]) * nscale;
            float e2 = __expf(s[2]) * nscale, e3 = __expf(s[3]) * nscale;
            uint2 pk;
            pk.x = (unsigned)f2bf(e0) | ((unsigned)f2bf(e1) << 16);
            pk.y = (unsigned)f2bf(e2) | ((unsigned)f2bf(e3) << 16);
            *(uint2*)&Ps[prow + kt*16 + g*4] = pk;
        }
        __syncthreads();
        {
            float acc = 0.f;
            #pragma unroll
            for (int wv = 0; wv < 8; wv++)
                acc += bf2f(Ps[(wv*16 + q2)*40 + key2]);
            srow[kbase] = acc;
        }
        __syncthreads();
    }
}

// out = LN(a + bres) * g + beta; one WAVE per row (float4 I/O, no LDS)
__global__ __launch_bounds__(256) void add_ln_kernel(
    const float* __restrict__ a, const float* __restrict__ bres,
    const float* __restrict__ g, const float* __restrict__ beta,
    float* __restrict__ out, ushort* __restrict__ out_bf)
{
    const int wv = threadIdx.x >> 6, lane = threadIdx.x & 63;
    const int r = blockIdx.x * 4 + wv;
    const size_t base = (size_t)r * H + lane * 4;
    float4 va = *(const float4*)&a[base];
    float4 vb = *(const float4*)&bres[base];
    float x0 = va.x + vb.x, x1 = va.y + vb.y, x2 = va.z + vb.z, x3 = va.w + vb.w;
    float s = (x0 + x1) + (x2 + x3);
    #pragma unroll
    for (int m = 1; m < 64; m <<= 1) s += __shfl_xor(s, m);
    const float mu = s * (1.f / 256.f);
    float d0 = x0 - mu, d1 = x1 - mu, d2 = x2 - mu, d3 = x3 - mu;
    float s2 = (d0*d0 + d1*d1) + (d2*d2 + d3*d3);
    #pragma unroll
    for (int m = 1; m < 64; m <<= 1) s2 += __shfl_xor(s2, m);
    const float rs = rsqrtf(s2 * (1.f / 256.f) + 1e-6f);
    float4 gv = *(const float4*)&g[lane*4];
    float4 bv = *(const float4*)&beta[lane*4];
    float4 o;
    o.x = d0 * rs * gv.x + bv.x;
    o.y = d1 * rs * gv.y + bv.y;
    o.z = d2 * rs * gv.z + bv.z;
    o.w = d3 * rs * gv.w + bv.w;
    *(float4*)&out[base] = o;
    if (out_bf) {
        ushort4 ob = { f2bf(o.x), f2bf(o.y), f2bf(o.z), f2bf(o.w) };
        *(ushort4*)&out_bf[base] = ob;
    }
}

extern "C" void kernel_launch(void* const* d_in, const int* in_sizes, int n_in,
                              void* d_out, int out_size, void* d_ws, size_t ws_size,
                              hipStream_t stream)
{
    const float* hidden = (const float*)d_in[0];
    const float* scene  = (const float*)d_in[1];
    const float* in_w   = (const float*)d_in[2];
    const float* in_b   = (const float*)d_in[3];
    const float* out_w  = (const float*)d_in[4];
    const float* out_b  = (const float*)d_in[5];
    const float* aln_g  = (const float*)d_in[6];
    const float* aln_b  = (const float*)d_in[7];
    const float* ff1_w  = (const float*)d_in[8];
    const float* ff1_b  = (const float*)d_in[9];
    const float* ff2_w  = (const float*)d_in[10];
    const float* ff2_b  = (const float*)d_in[11];
    const float* fln_g  = (const float*)d_in[12];
    const float* fln_b  = (const float*)d_in[13];

    float* out0  = (float*)d_out;
    float* score = out0 + (size_t)BATCH * MQ * H;

    ushort* hbf  = (ushort*)d_ws;                    // 16384x256
    ushort* sbf  = hbf  + 4194304;                   // 2048x256
    ushort* wqkv = sbf  + 524288;                    // 768x256
    ushort* wo   = wqkv + 196608;                    // 256x256
    ushort* w1   = wo   + 65536;                     // 128x256
    ushort* w2   = w1   + 32768;                     // 256x128
    ushort* qb   = w2   + 32768;                     // 16384x256
    ushort* kb   = qb   + 4194304;                   // 2048x256
    ushort* vtb  = kb   + 524288;                    // [b][256][512]
    ushort* ctxb = vtb  + 524288;                    // 16384x256
    ushort* xbh  = ctxb + 4194304;                   // 16384x256
    ushort* fb   = xbh  + 4194304;                   // 16384x128
    float*  att  = (float*)(fb + 2097152);           // 16384x256 f32 (also y)
    float*  xb   = att + 4194304;                    // 16384x256 f32

    const float scale = 0.17677669529663687f;        // 1/sqrt(32)

    CvtArgs ca;
    ca.src[0]=hidden; ca.dst[0]=hbf;  ca.n[0]=4194304;
    ca.src[1]=scene;  ca.dst[1]=sbf;  ca.n[1]=524288;
    ca.src[2]=in_w;   ca.dst[2]=wqkv; ca.n[2]=196608;
    ca.src[3]=out_w;  ca.dst[3]=wo;   ca.n[3]=65536;
    ca.src[4]=ff1_w;  ca.dst[4]=w1;   ca.n[4]=32768;
    ca.src[5]=ff2_w;  ca.dst[5]=w2;   ca.n[5]=32768;
    cvt_kernel<<<dim3(2048, 6), dim3(256), 0, stream>>>(ca);

    // q = bf16((hidden @ Wq^T + bq) * scale)
    gemm_bf16_kernel<<<dim3(2, 128), dim3(256), 0, stream>>>(
        hbf, wqkv, in_b, qb, (ushort*)0, 256, 256, scale, 0, 1);
    // k (row-major) + vT (transposed) in one GEMM: W rows 256..767 of in_proj
    gemm_bf16_kernel<<<dim3(4, 16), dim3(256), 0, stream>>>(
        sbf, wqkv + 65536, in_b + 256, kb, vtb, 256, 512, 1.f, 0, 3);
    // fused MFMA attention -> ctx (bf16) + attn_score
    attn_mfma_kernel<<<dim3(1024), dim3(512), 0, stream>>>(qb, kb, vtb, ctxb, score);
    // attn_out = ctx @ Wout^T + bout  (f32)
    gemm_bf16_kernel<<<dim3(2, 128), dim3(256), 0, stream>>>(
        ctxb, wo, out_b, att, (ushort*)0, 256, 256, 1.f, 0, 0);
    // x = LN(attn_out + hidden)  (f32 + bf16)
    add_ln_kernel<<<dim3(4096), dim3(256), 0, stream>>>(att, hidden, aln_g, aln_b, xb, xbh);
    // f = bf16(relu(x @ W1^T + b1))
    gemm_bf16_kernel<<<dim3(1, 128), dim3(256), 0, stream>>>(
        xbh, w1, ff1_b, fb, (ushort*)0, 256, 128, 1.f, 1, 1);
    // y = f @ W2^T + b2  (f32)
    gemm_bf16_kernel<<<dim3(2, 128), dim3(256), 0, stream>>>(
        fb, w2, ff2_b, att, (ushort*)0, 128, 256, 1.f, 0, 0);
    // out = LN(y + x)
    add_ln_kernel<<<dim3(4096), dim3(256), 0, stream>>>(att, xb, fln_g, fln_b, out0, (ushort*)0);
}

// Round 5
// 256.180 us; speedup vs baseline: 3.2948x; 1.1110x over previous
//
#include <hip/hip_runtime.h>
#include <hip/hip_bf16.h>

#define H 256
#define NSC 512
#define MQ 4096
#define BATCH 4

typedef __attribute__((ext_vector_type(8))) short bf16x8;
typedef __attribute__((ext_vector_type(4))) float f32x4;

__device__ __forceinline__ ushort f2bf(float x) {
    union { float f; unsigned u; } c; c.f = x;
    unsigned r = c.u + 0x7FFF + ((c.u >> 16) & 1);   // RNE
    return (ushort)(r >> 16);
}
// pack hi16(lo),hi16(hi) -> one dword (bf16 truncation, 1 v_perm)
__device__ __forceinline__ unsigned pk2(float hi, float lo) {
    union { float f; unsigned u; } a, b; a.f = hi; b.f = lo;
    return __builtin_amdgcn_perm(a.u, b.u, 0x07060302u);
}
__device__ __forceinline__ uint4 cvt8f(const float* p) {
    float4 a = *(const float4*)p;
    float4 b = *(const float4*)(p + 4);
    uint4 r;
    r.x = pk2(a.y, a.x); r.y = pk2(a.w, a.z);
    r.z = pk2(b.y, b.x); r.w = pk2(b.w, b.z);
    return r;
}

// ---- bf16 MFMA GEMM, block = 64 rows x 256 cols, 512 thr = 8 waves (2x4).
// A: f32 (ATYPE 0) or bf16 (ATYPE 1); W always f32, converted during staging.
// MODE 0: D = bf16(act((A@W^T + bias)*alpha)), stride N, cols guarded by N.
// MODE 1: kv split: col<256 -> bf16 k[row*256+col]; col>=256 -> vT
//         out2[((row>>9)*256 + col-256)*512 + (row&511)].
// MODE 2: fused add+LN: v = A@W^T + bias + res; LN over the 256-col row;
//         f32 out [row*256+col], optional bf16 out2.
template<int ATYPE, int MODE>
__global__ __launch_bounds__(512, 4) void gemm_kernel(
    const void* __restrict__ Ain, const float* __restrict__ W,
    const float* __restrict__ bias, const float* __restrict__ res,
    const float* __restrict__ lng, const float* __restrict__ lnb,
    void* __restrict__ out, ushort* __restrict__ out2,
    int K, int N, float alpha, int relu)
{
    __shared__ ushort As[64 * 64];
    __shared__ ushort Bs[256 * 64];
    __shared__ float Ls[64 * 4];
    __shared__ float Lq[64 * 4];
    const int t = threadIdx.x;
    const int w = t >> 6, lane = t & 63, g = lane >> 4, l15 = lane & 15;
    const int rowBase = blockIdx.y * 64;
    const int colBase = blockIdx.x * 256;
    const int wr = (w >> 2) * 32;
    const int wc = (w & 3) * 64;
    f32x4 acc[2][4];
    #pragma unroll
    for (int mt = 0; mt < 2; mt++)
        #pragma unroll
        for (int nt = 0; nt < 4; nt++) acc[mt][nt] = (f32x4){0.f,0.f,0.f,0.f};

    const int sr = t >> 3, skc = t & 7, sp = skc ^ (sr & 7);

    for (int k0 = 0; k0 < K; k0 += 64) {
        uint4 av;
        if (ATYPE == 0) {
            av = cvt8f((const float*)Ain + (size_t)(rowBase + sr) * K + k0 + skc*8);
        } else {
            av = *(const uint4*)((const ushort*)Ain + (size_t)(rowBase + sr) * K + k0 + skc*8);
        }
        uint4 bv[4];
        #pragma unroll
        for (int i = 0; i < 4; i++) {
            const int u = t + 512*i, br = u >> 3, bkc = u & 7;
            int brow = colBase + br; if (brow > N - 1) brow = N - 1;
            bv[i] = cvt8f(W + (size_t)brow * K + k0 + bkc*8);
        }
        __syncthreads();
        *(uint4*)&As[sr*64 + sp*8] = av;
        #pragma unroll
        for (int i = 0; i < 4; i++) {
            const int u = t + 512*i, br = u >> 3, bkc = u & 7, bp = bkc ^ (br & 7);
            *(uint4*)&Bs[br*64 + bp*8] = bv[i];
        }
        __syncthreads();
        #pragma unroll
        for (int kk = 0; kk < 2; kk++) {
            const int swz = ((kk*4 + g) ^ (l15 & 7)) * 8;
            bf16x8 af[2], bfr[4];
            #pragma unroll
            for (int mt = 0; mt < 2; mt++)
                af[mt] = *(const bf16x8*)&As[(wr + mt*16 + l15)*64 + swz];
            #pragma unroll
            for (int nt = 0; nt < 4; nt++)
                bfr[nt] = *(const bf16x8*)&Bs[(wc + nt*16 + l15)*64 + swz];
            #pragma unroll
            for (int mt = 0; mt < 2; mt++)
                #pragma unroll
                for (int nt = 0; nt < 4; nt++)
                    acc[mt][nt] = __builtin_amdgcn_mfma_f32_16x16x32_bf16(
                        af[mt], bfr[nt], acc[mt][nt], 0, 0, 0);
        }
    }

    if (MODE == 0) {
        #pragma unroll
        for (int nt = 0; nt < 4; nt++) {
            const int col = colBase + wc + nt*16 + l15;
            if (col < N) {
                const float bb = bias[col];
                #pragma unroll
                for (int mt = 0; mt < 2; mt++)
                    #pragma unroll
                    for (int r = 0; r < 4; r++) {
                        const int row = rowBase + wr + mt*16 + g*4 + r;
                        float o = (acc[mt][nt][r] + bb) * alpha;
                        if (relu) o = fmaxf(o, 0.f);
                        ((ushort*)out)[(size_t)row * N + col] = f2bf(o);
                    }
            }
        }
    } else if (MODE == 1) {
        #pragma unroll
        for (int nt = 0; nt < 4; nt++) {
            const int col = colBase + wc + nt*16 + l15;
            const float bb = bias[col];
            #pragma unroll
            for (int mt = 0; mt < 2; mt++) {
                const int row0 = rowBase + wr + mt*16 + g*4;
                if (col < 256) {
                    #pragma unroll
                    for (int r = 0; r < 4; r++)
                        ((ushort*)out)[(size_t)(row0 + r) * 256 + col] = f2bf(acc[mt][nt][r] + bb);
                } else {
                    ushort4 pkv = { f2bf(acc[mt][nt][0] + bb), f2bf(acc[mt][nt][1] + bb),
                                    f2bf(acc[mt][nt][2] + bb), f2bf(acc[mt][nt][3] + bb) };
                    *(ushort4*)&out2[(size_t)((row0 >> 9)*256 + col - 256) * 512 + (row0 & 511)] = pkv;
                }
            }
        }
    } else {
        float bb[4], gmv[4], btv[4];
        #pragma unroll
        for (int nt = 0; nt < 4; nt++) {
            const int col = wc + nt*16 + l15;
            bb[nt] = bias[col]; gmv[nt] = lng[col]; btv[nt] = lnb[col];
        }
        #pragma unroll
        for (int mt = 0; mt < 2; mt++)
            #pragma unroll
            for (int r = 0; r < 4; r++) {
                const int row = rowBase + wr + mt*16 + g*4 + r;
                const float* rp = res + (size_t)row * 256;
                #pragma unroll
                for (int nt = 0; nt < 4; nt++)
                    acc[mt][nt][r] += bb[nt] + rp[wc + nt*16 + l15];
            }
        float ps[2][4], pq[2][4];
        #pragma unroll
        for (int mt = 0; mt < 2; mt++)
            #pragma unroll
            for (int r = 0; r < 4; r++) {
                float s = (acc[mt][0][r] + acc[mt][1][r]) + (acc[mt][2][r] + acc[mt][3][r]);
                float qq = (acc[mt][0][r]*acc[mt][0][r] + acc[mt][1][r]*acc[mt][1][r])
                         + (acc[mt][2][r]*acc[mt][2][r] + acc[mt][3][r]*acc[mt][3][r]);
                #pragma unroll
                for (int m = 1; m < 16; m <<= 1) {
                    s += __shfl_xor(s, m);
                    qq += __shfl_xor(qq, m);
                }
                ps[mt][r] = s; pq[mt][r] = qq;
            }
        if (l15 == 0) {
            #pragma unroll
            for (int mt = 0; mt < 2; mt++)
                #pragma unroll
                for (int r = 0; r < 4; r++) {
                    const int ri = wr + mt*16 + g*4 + r;
                    Ls[ri*4 + (w & 3)] = ps[mt][r];
                    Lq[ri*4 + (w & 3)] = pq[mt][r];
                }
        }
        __syncthreads();
        #pragma unroll
        for (int mt = 0; mt < 2; mt++)
            #pragma unroll
            for (int r = 0; r < 4; r++) {
                const int ri = wr + mt*16 + g*4 + r;
                const int row = rowBase + ri;
                f32x4 sv = *(const f32x4*)&Ls[ri*4];
                f32x4 qv = *(const f32x4*)&Lq[ri*4];
                const float mu = (sv[0]+sv[1]+sv[2]+sv[3]) * (1.f/256.f);
                const float ex2 = (qv[0]+qv[1]+qv[2]+qv[3]) * (1.f/256.f);
                const float rs = rsqrtf(ex2 - mu*mu + 1e-6f);
                #pragma unroll
                for (int nt = 0; nt < 4; nt++) {
                    const int col = wc + nt*16 + l15;
                    const float o = (acc[mt][nt][r] - mu) * rs * gmv[nt] + btv[nt];
                    ((float*)out)[(size_t)row * 256 + col] = o;
                    if (out2) out2[(size_t)row * 256 + col] = f2bf(o);
                }
            }
    }
}

// ---- Flash MFMA cross-attention, S^T formulation, log2 domain.
// q is pre-scaled by (1/sqrt(d))*log2(e) so p = exp2(s).
// Block = 512 thr = 8 waves, 16 queries, grid 1024. Pass 1: wave = head,
// K/V direct from global (L2), P transposed via per-wave swizzled LDS
// roundtrip (no barriers). Pass 2: wave = 2 key-chunks x ALL heads,
// head-mean in registers, coalesced f32x4 score writes. One barrier total.
__global__ __launch_bounds__(512, 4) void attn_mfma_kernel(
    const ushort* __restrict__ q, const ushort* __restrict__ k,
    const ushort* __restrict__ vt, ushort* __restrict__ ctx_out,
    float* __restrict__ attn_score)
{
    __shared__ ushort Ps[8 * 16 * 40];   // per-wave [16 q][32 keys + pad], swizzled 16B chunks
    __shared__ float Ls[128];            // lgl per (head, q)
    const int t = threadIdx.x;
    const int w = t >> 6;
    const int lane = t & 63;
    const int g = lane >> 4;
    const int l15 = lane & 15;
    const int b = blockIdx.x >> 8;
    const int m0 = (blockIdx.x & 255) * 16;

    const size_t qrow = (size_t)(b*MQ + m0 + l15) * H;
    const size_t kg = (size_t)b * NSC * H;
    const size_t vg = (size_t)b * H * NSC;

    const int prow = (w*16 + l15) * 40;
    const int sw = l15 & 3;
    const int wi0 = prow + ((0 + (g>>1)) ^ sw)*8 + (g&1)*4;   // kt=0 write (uint2)
    const int wi1 = prow + ((2 + (g>>1)) ^ sw)*8 + (g&1)*4;   // kt=1 write
    const int ri  = prow + (g ^ sw)*8;                         // b128 read

    const bf16x8 qf_own = *(const bf16x8*)&q[qrow + w*32 + g*8];

    f32x4 cacc[2];
    cacc[0] = (f32x4){0.f,0.f,0.f,0.f};
    cacc[1] = (f32x4){0.f,0.f,0.f,0.f};
    float lacc = 0.f;

    // ---- pass 1: denominators + ctx (no barriers) ----
    for (int c = 0; c < 16; c++) {
        const int kbase = c * 32;
        #pragma unroll
        for (int kt = 0; kt < 2; kt++) {
            bf16x8 kf = *(const bf16x8*)&k[kg + (size_t)(kbase + kt*16 + l15)*H + w*32 + g*8];
            f32x4 s = __builtin_amdgcn_mfma_f32_16x16x32_bf16(
                kf, qf_own, (f32x4){0.f,0.f,0.f,0.f}, 0, 0, 0);
            float e0 = exp2f(s[0]), e1 = exp2f(s[1]);
            float e2 = exp2f(s[2]), e3 = exp2f(s[3]);
            lacc += (e0 + e1) + (e2 + e3);
            uint2 pkv;
            pkv.x = pk2(e1, e0);
            pkv.y = pk2(e3, e2);
            *(uint2*)&Ps[kt ? wi1 : wi0] = pkv;
        }
        bf16x8 pf = *(const bf16x8*)&Ps[ri];
        #pragma unroll
        for (int dt = 0; dt < 2; dt++) {
            bf16x8 vf = *(const bf16x8*)&vt[vg + (size_t)(w*32 + dt*16 + l15)*NSC + kbase + g*8];
            cacc[dt] = __builtin_amdgcn_mfma_f32_16x16x32_bf16(pf, vf, cacc[dt], 0, 0, 0);
        }
    }

    float lsum = lacc;
    lsum += __shfl_xor(lsum, 16);
    lsum += __shfl_xor(lsum, 32);
    const float invl = 1.f / lsum;

    float invl_r[4];
    #pragma unroll
    for (int r = 0; r < 4; r++) invl_r[r] = __shfl(invl, g*4 + r);
    #pragma unroll
    for (int dt = 0; dt < 2; dt++)
        #pragma unroll
        for (int r = 0; r < 4; r++)
            ctx_out[((size_t)(b*MQ + m0 + g*4 + r))*H + w*32 + dt*16 + l15]
                = f2bf(cacc[dt][r] * invl_r[r]);

    if (lane < 16) Ls[w*16 + lane] = -log2f(lsum) - 3.0f;   // folds 1/l and 1/8
    __syncthreads();

    // ---- pass 2: score = mean over heads; wave handles chunks w, w+8 ----
    float lgl[8];
    #pragma unroll
    for (int h = 0; h < 8; h++) lgl[h] = Ls[h*16 + l15];
    bf16x8 qf2[8];
    #pragma unroll
    for (int h = 0; h < 8; h++) qf2[h] = *(const bf16x8*)&q[qrow + h*32 + g*8];

    #pragma unroll
    for (int cc = 0; cc < 2; cc++) {
        const int kbase = (w + cc*8) * 32;
        f32x4 a0 = (f32x4){0.f,0.f,0.f,0.f};
        f32x4 a1 = (f32x4){0.f,0.f,0.f,0.f};
        #pragma unroll
        for (int h = 0; h < 8; h++) {
            #pragma unroll
            for (int kt = 0; kt < 2; kt++) {
                bf16x8 kf = *(const bf16x8*)&k[kg + (size_t)(kbase + kt*16 + l15)*H + h*32 + g*8];
                f32x4 s = __builtin_amdgcn_mfma_f32_16x16x32_bf16(
                    kf, qf2[h], (f32x4){0.f,0.f,0.f,0.f}, 0, 0, 0);
                if (kt == 0) {
                    #pragma unroll
                    for (int r = 0; r < 4; r++) a0[r] += exp2f(s[r] + lgl[h]);
                } else {
                    #pragma unroll
                    for (int r = 0; r < 4; r++) a1[r] += exp2f(s[r] + lgl[h]);
                }
            }
        }
        float* sp = &attn_score[((size_t)(b*MQ + m0 + l15))*NSC + kbase + g*4];
        *(f32x4*)sp = a0;
        *(f32x4*)(sp + 16) = a1;
    }
}

extern "C" void kernel_launch(void* const* d_in, const int* in_sizes, int n_in,
                              void* d_out, int out_size, void* d_ws, size_t ws_size,
                              hipStream_t stream)
{
    const float* hidden = (const float*)d_in[0];
    const float* scene  = (const float*)d_in[1];
    const float* in_w   = (const float*)d_in[2];
    const float* in_b   = (const float*)d_in[3];
    const float* out_w  = (const float*)d_in[4];
    const float* out_b  = (const float*)d_in[5];
    const float* aln_g  = (const float*)d_in[6];
    const float* aln_b  = (const float*)d_in[7];
    const float* ff1_w  = (const float*)d_in[8];
    const float* ff1_b  = (const float*)d_in[9];
    const float* ff2_w  = (const float*)d_in[10];
    const float* ff2_b  = (const float*)d_in[11];
    const float* fln_g  = (const float*)d_in[12];
    const float* fln_b  = (const float*)d_in[13];

    float* out0  = (float*)d_out;
    float* score = out0 + (size_t)BATCH * MQ * H;

    ushort* qb   = (ushort*)d_ws;                    // 16384x256 bf16
    ushort* kb   = qb   + 4194304;                   // 2048x256 bf16
    ushort* vtb  = kb   + 524288;                    // [b][256][512] bf16
    ushort* ctxb = vtb  + 524288;                    // 16384x256 bf16
    ushort* xbh  = ctxb + 4194304;                   // 16384x256 bf16
    ushort* fb   = xbh  + 4194304;                   // 16384x128 bf16
    float*  xb   = (float*)(fb + 2097152);           // 16384x256 f32

    // (1/sqrt(32)) * log2(e): q pre-scaled so attn uses exp2 directly
    const float alpha_q = 0.25507609683638066f;
    dim3 blk(512);

    // q = bf16((hidden @ Wq^T + bq) * alpha_q)
    gemm_kernel<0,0><<<dim3(1,256), blk, 0, stream>>>(
        hidden, in_w, in_b, nullptr, nullptr, nullptr, qb, nullptr, 256, 256, alpha_q, 0);
    // k (bf16 row-major) + vT (bf16 transposed) in one GEMM
    gemm_kernel<0,1><<<dim3(2,32), blk, 0, stream>>>(
        scene, in_w + 65536, in_b + 256, nullptr, nullptr, nullptr, kb, vtb, 256, 512, 1.f, 0);
    // fused MFMA attention -> ctx bf16 + attn_score f32
    attn_mfma_kernel<<<dim3(1024), blk, 0, stream>>>(qb, kb, vtb, ctxb, score);
    // x = LN(ctx @ Wout^T + bout + hidden): f32 xb + bf16 xbh
    gemm_kernel<1,2><<<dim3(1,256), blk, 0, stream>>>(
        ctxb, out_w, out_b, hidden, aln_g, aln_b, xb, xbh, 256, 256, 1.f, 0);
    // f = bf16(relu(x @ W1^T + b1))
    gemm_kernel<1,0><<<dim3(1,256), blk, 0, stream>>>(
        xbh, ff1_w, ff1_b, nullptr, nullptr, nullptr, fb, nullptr, 256, 128, 1.f, 1);
    // out = LN(f @ W2^T + b2 + x)
    gemm_kernel<1,2><<<dim3(1,256), blk, 0, stream>>>(
        fb, ff2_w, ff2_b, xb, fln_g, fln_b, out0, nullptr, 128, 256, 1.f, 0);
}